// Round 13
// baseline (629.194 us; speedup 1.0000x reference)
//
#include <hip/hip_runtime.h>
#include <hip/hip_bf16.h>

#define DEV __device__ __forceinline__

DEV float bf2f(__hip_bfloat16 v) { return __bfloat162float(v); }

typedef unsigned long long ull;

// ---------------- fused ingest + tower mask + degree count (+rank) ----------
// Each block self-detects the input dtype from an 8 KB probe (L2-hot
// broadcast); cnt is zeroed by hipMemsetAsync. Block 0 publishes flag.
struct Seg  { const void* src; int off; int len; };
struct Segs { Seg s[22]; };

__global__ void k_fused(const void* xsrc, int nx3, int nprobe, Segs segs,
                        float* canon, int* flag, const int* eidx, int E, int N,
                        int* cnt, int* msk, int* rank) {
    __shared__ int red[256];
    int t = threadIdx.x, b = blockIdx.x;
    const unsigned short* xr = (const unsigned short*)xsrc;
    int bad = 0;
    for (int j = t; j < nprobe; j += 256) {
        unsigned e = (xr[j] >> 7) & 0xFF;
        if (e >= 0x8F) bad++;    // |v| >= 2^16: impossible for true bf16 N(0,1)
    }
    red[t] = bad; __syncthreads();
    for (int o = 128; o > 0; o >>= 1) { if (t < o) red[t] += red[t + o]; __syncthreads(); }
    int f32 = (red[0] > 256) ? 1 : 0;
    if (b == 0 && t == 0) flag[0] = f32;

    if (b < 64) {
        for (int i = b * 256 + t; i < nx3; i += 64 * 256) {
            float v = f32 ? ((const float*)xsrc)[i] : bf2f(((const __hip_bfloat16*)xsrc)[i]);
            if (!(v == v) || fabsf(v) > 1e30f) v = 0.f;   // scrub
            canon[i] = v;
            if (i % 3 == 0) msk[i / 3] = (v == 0.0f) ? 1 : 0;
        }
    } else if (b < 86) {
        Seg sg = segs.s[b - 64];
        for (int i = t; i < sg.len; i += 256) {
            float v = f32 ? ((const float*)sg.src)[i] : bf2f(((const __hip_bfloat16*)sg.src)[i]);
            if (!(v == v) || fabsf(v) > 1e30f) v = 0.f;
            canon[sg.off + i] = v;
        }
    } else {
        int e = (b - 86) * 256 + t;
        if (e < E) {
            int d = eidx[E + e];
            if ((unsigned)d < (unsigned)N) {
                int p = atomicAdd(&cnt[d], 1);
                rank[e] = p;        // rank within dst bucket -> atomic-free fill
            }
        }
    }
}

// ---------------- packed 64-bit exclusive scan ------------------------------

DEV ull packval(const int* cnt, const int* msk, int i) {
    return ((ull)(unsigned)msk[i] << 32) | (unsigned)(cnt[i] + 1);
}

__global__ void k_scan_partial64(const int* __restrict__ cnt, const int* __restrict__ msk,
                                 int n, ull* __restrict__ partials) {
    __shared__ ull red[256];
    int t = threadIdx.x, b = blockIdx.x;
    int base = b * 1024 + t * 4;
    ull s = 0;
    #pragma unroll
    for (int j = 0; j < 4; j++) { int i = base + j; if (i < n) s += packval(cnt, msk, i); }
    red[t] = s; __syncthreads();
    for (int o = 128; o > 0; o >>= 1) { if (t < o) red[t] += red[t + o]; __syncthreads(); }
    if (t == 0) partials[b] = red[0];
}

__global__ void k_scan_final64(const int* __restrict__ cnt, int* __restrict__ msk, int n,
                               const ull* __restrict__ partials, int nb,
                               int* __restrict__ off, int* __restrict__ offN,
                               int* __restrict__ totals) {
    __shared__ ull sums[256];
    __shared__ ull redLT[256], redALL[256];
    int t = threadIdx.x, b = blockIdx.x;

    ull sLT = 0, sALL = 0;
    for (int i = t; i < nb; i += 256) {
        ull v = partials[i];
        sALL += v;
        if (i < b) sLT += v;
    }
    redLT[t] = sLT; redALL[t] = sALL; __syncthreads();
    for (int o = 128; o > 0; o >>= 1) {
        if (t < o) { redLT[t] += redLT[t + o]; redALL[t] += redALL[t + o]; }
        __syncthreads();
    }
    ull blockbase = redLT[0];
    if (b == 0 && t == 0) {
        ull tot = redALL[0];
        *offN = (int)(tot & 0xffffffffu);
        *totals = (int)(tot >> 32);
    }
    __syncthreads();

    int base = b * 1024 + t * 4;
    ull v0 = 0, v1 = 0, v2 = 0, v3 = 0;
    if (base     < n) v0 = packval(cnt, msk, base);
    if (base + 1 < n) v1 = packval(cnt, msk, base + 1);
    if (base + 2 < n) v2 = packval(cnt, msk, base + 2);
    if (base + 3 < n) v3 = packval(cnt, msk, base + 3);
    ull s = v0 + v1 + v2 + v3;
    sums[t] = s; __syncthreads();
    for (int o = 1; o < 256; o <<= 1) {
        ull x = (t >= o) ? sums[t - o] : 0;
        __syncthreads();
        sums[t] += x;
        __syncthreads();
    }
    ull run = blockbase + (sums[t] - s);
    #pragma unroll
    for (int j = 0; j < 4; j++) {
        int i = base + j;
        if (i < n) {
            off[i] = (int)(run & 0xffffffffu);
            msk[i] = (int)(run >> 32);
            run += (j == 0 ? v0 : j == 1 ? v1 : j == 2 ? v2 : v3);
        }
    }
}

// ---------------- fused CSR fill (atomic-free) + GAT layer-1 node -----------

__global__ __launch_bounds__(256) void k_fill_node1(
    const int* __restrict__ eidx, const int* __restrict__ rank, int E, int N,
    const int* __restrict__ off, int* __restrict__ esrc,
    const float* __restrict__ xF, const float* __restrict__ W,
    const float* __restrict__ atS, const float* __restrict__ atD,
    __hip_bfloat162* __restrict__ h2, float* __restrict__ as_, float* __restrict__ ad_,
    int gfill) {
    __shared__ float xl[64 * 4];
    int b = blockIdx.x;
    if (b < gfill) {
        int e = b * 256 + threadIdx.x;
        if (e < E) {
            int s = eidx[e], d = eidx[E + e];
            if ((unsigned)d < (unsigned)N && (unsigned)s < (unsigned)N)
                esrc[off[d] + rank[e]] = s;
        } else if (e < E + N) {
            int i = e - E;
            esrc[off[i + 1] - 1] = i;   // self-loop in the last slot
        }
        return;
    }
    int t = threadIdx.x, lane = t & 63, w = t >> 6;
    int nblk = (b - gfill) * 64;
    int cnt = N - nblk; if (cnt > 64) cnt = 64;

    if (t < 64) xl[t * 4 + 3] = 0.f;
    for (int i = t; i < cnt * 3; i += 256) xl[(i / 3) * 4 + (i % 3)] = xF[(size_t)nblk * 3 + i];

    const float2* W2 = (const float2*)W;
    float2 Wr0 = W2[0 * 64 + lane], Wr1 = W2[1 * 64 + lane], Wr2 = W2[2 * 64 + lane];
    float2 aSp = ((const float2*)atS)[lane];
    float2 aDp = ((const float2*)atD)[lane];
    int hd = lane >> 4;
    __syncthreads();

    for (int i = 0; i < 16; i++) {
        int n = nblk + w * 16 + i;
        if (n >= N) break;
        float4 xv = ((const float4*)xl)[w * 16 + i];
        float acc0 = xv.x * Wr0.x + xv.y * Wr1.x + xv.z * Wr2.x;
        float acc1 = xv.x * Wr0.y + xv.y * Wr1.y + xv.z * Wr2.y;
        __hip_bfloat162 hv; hv.x = __float2bfloat16(acc0); hv.y = __float2bfloat16(acc1);
        h2[(size_t)n * 64 + lane] = hv;
        float p = acc0 * aSp.x + acc1 * aSp.y;
        float q = acc0 * aDp.x + acc1 * aDp.y;
        #pragma unroll
        for (int o = 1; o < 16; o <<= 1) { p += __shfl_xor(p, o, 64); q += __shfl_xor(q, o, 64); }
        if ((lane & 15) == 0) { as_[n * 4 + hd] = p; ad_[n * 4 + hd] = q; }
    }
}

// ---------------- GAT node kernel (layers 2,3) ------------------------------

__global__ __launch_bounds__(256) void k_node_mid(
    const float* __restrict__ xin, const float* __restrict__ W,
    const float* __restrict__ atS, const float* __restrict__ atD,
    int N, __hip_bfloat162* __restrict__ h2, float* __restrict__ as_, float* __restrict__ ad_) {
    __shared__ float xl[64 * 32];
    int t = threadIdx.x, lane = t & 63, w = t >> 6;
    int nblk = blockIdx.x * 64;
    int cnt = N - nblk; if (cnt > 64) cnt = 64;

    {
        const float4* g4 = (const float4*)(xin + (size_t)nblk * 32);
        float4* l4 = (float4*)xl;
        int lim = cnt * 8;
        if (t < lim) l4[t] = g4[t];
        int t2 = t + 256;
        if (t2 < lim) l4[t2] = g4[t2];
    }

    const float2* W2 = (const float2*)W;
    float2 Wr[32];
    #pragma unroll
    for (int k = 0; k < 32; k++) Wr[k] = W2[k * 64 + lane];
    float2 aSp = ((const float2*)atS)[lane];
    float2 aDp = ((const float2*)atD)[lane];
    int hd = lane >> 4;
    __syncthreads();

    for (int i = 0; i < 16; i++) {
        int n = nblk + w * 16 + i;
        if (n >= N) break;
        const float4* xv4 = (const float4*)&xl[(w * 16 + i) * 32];
        float acc0 = 0.f, acc1 = 0.f;
        #pragma unroll
        for (int kk = 0; kk < 8; kk++) {
            float4 xv = xv4[kk];
            acc0 += xv.x * Wr[4*kk+0].x; acc1 += xv.x * Wr[4*kk+0].y;
            acc0 += xv.y * Wr[4*kk+1].x; acc1 += xv.y * Wr[4*kk+1].y;
            acc0 += xv.z * Wr[4*kk+2].x; acc1 += xv.z * Wr[4*kk+2].y;
            acc0 += xv.w * Wr[4*kk+3].x; acc1 += xv.w * Wr[4*kk+3].y;
        }
        __hip_bfloat162 hv; hv.x = __float2bfloat16(acc0); hv.y = __float2bfloat16(acc1);
        h2[(size_t)n * 64 + lane] = hv;
        float p = acc0 * aSp.x + acc1 * aSp.y;
        float q = acc0 * aDp.x + acc1 * aDp.y;
        #pragma unroll
        for (int o = 1; o < 16; o <<= 1) { p += __shfl_xor(p, o, 64); q += __shfl_xor(q, o, 64); }
        if ((lane & 15) == 0) { as_[n * 4 + hd] = p; ad_[n * 4 + hd] = q; }
    }
}

// ---------------- GAT edge kernel -------------------------------------------
// Shuffle-free fast path (deg<=16): every lane redundantly computes its
// head's full softmax in registers from broadcast esrc/as_ loads. FIX vs
// round-12: ex[] is forced to 0 for ALL padded slots i>=deg (round-12 left
// the -1e30 sentinel in padded slots of active chunks -> 1e30-scale garbage).

constexpr int FCAP  = 64;
constexpr int FCAPP = 68;

__global__ __launch_bounds__(256) void k_edge(
    const __hip_bfloat162* __restrict__ h2, const float* __restrict__ as_,
    const float* __restrict__ ad_, const int* __restrict__ off,
    const int* __restrict__ esrc, const float* __restrict__ bias,
    int N, float* __restrict__ xout) {
    __shared__ float alphaS[4][4 * FCAPP];
    __shared__ int   srcS[4][FCAP];
    int t = threadIdx.x, lane = t & 63, w = t >> 6;
    int n = blockIdx.x * 4 + w;
    if (n >= N) return;
    int beg = off[n], end = off[n + 1];
    int deg = end - beg;
    float4 adn = ((const float4*)ad_)[n];
    const float4* as4 = (const float4*)as_;
    int hd = lane >> 4;

    float acc0 = 0.f, acc1 = 0.f;

    if (deg <= 16) {
        float adH = hd == 0 ? adn.x : hd == 1 ? adn.y : hd == 2 ? adn.z : adn.w;
        int   ss[16];
        float sc[16];     // raw scores (sentinel -1e30 for pad/invalid)
        float ex[16];     // softmax numerators (0 for pad/invalid)
        float m = -1e30f;
        #pragma unroll
        for (int i = 0; i < 16; i++) {
            ss[i] = n; sc[i] = -1e30f;
            if (i < deg) {
                int s = esrc[beg + i];        // wave-broadcast load
                if ((unsigned)s < (unsigned)N) {
                    ss[i] = s;
                    float v = as_[s * 4 + hd] + adH;   // 4-way group-uniform load
                    v = v >= 0.f ? v : 0.2f * v;
                    sc[i] = v;
                    m = fmaxf(m, v);
                }
            }
        }
        float ssum = 0.f;
        #pragma unroll
        for (int i = 0; i < 16; i++) {
            float e = (sc[i] > -1e29f) ? __expf(sc[i] - m) : 0.f;   // pad -> 0
            ex[i] = e;
            ssum += e;
        }
        float invH = 1.f / (ssum + 1e-16f);
        #pragma unroll
        for (int c = 0; c < 4; c++) {
            if (4 * c < deg) {
                __hip_bfloat162 g0 = h2[(size_t)ss[4*c+0] * 64 + lane];
                __hip_bfloat162 g1 = h2[(size_t)ss[4*c+1] * 64 + lane];
                __hip_bfloat162 g2 = h2[(size_t)ss[4*c+2] * 64 + lane];
                __hip_bfloat162 g3 = h2[(size_t)ss[4*c+3] * 64 + lane];
                acc0 += ex[4*c+0] * bf2f(g0.x) + ex[4*c+1] * bf2f(g1.x)
                      + ex[4*c+2] * bf2f(g2.x) + ex[4*c+3] * bf2f(g3.x);
                acc1 += ex[4*c+0] * bf2f(g0.y) + ex[4*c+1] * bf2f(g1.y)
                      + ex[4*c+2] * bf2f(g2.y) + ex[4*c+3] * bf2f(g3.y);
            }
        }
        acc0 *= invH; acc1 *= invH;
    } else {
        bool fits = (deg <= FCAP);
        float m0 = -1e30f, m1 = -1e30f, m2 = -1e30f, m3 = -1e30f;
        for (int e = beg + lane; e < end; e += 64) {
            int s = esrc[e];
            if ((unsigned)s >= (unsigned)N) continue;
            float4 a = as4[s];
            float v0 = a.x + adn.x; v0 = v0 >= 0.f ? v0 : 0.2f * v0;
            float v1 = a.y + adn.y; v1 = v1 >= 0.f ? v1 : 0.2f * v1;
            float v2 = a.z + adn.z; v2 = v2 >= 0.f ? v2 : 0.2f * v2;
            float v3 = a.w + adn.w; v3 = v3 >= 0.f ? v3 : 0.2f * v3;
            m0 = fmaxf(m0, v0); m1 = fmaxf(m1, v1); m2 = fmaxf(m2, v2); m3 = fmaxf(m3, v3);
        }
        #pragma unroll
        for (int o = 1; o < 64; o <<= 1) {
            m0 = fmaxf(m0, __shfl_xor(m0, o, 64));
            m1 = fmaxf(m1, __shfl_xor(m1, o, 64));
            m2 = fmaxf(m2, __shfl_xor(m2, o, 64));
            m3 = fmaxf(m3, __shfl_xor(m3, o, 64));
        }
        float s0 = 0.f, s1 = 0.f, s2 = 0.f, s3 = 0.f;
        for (int e = beg + lane; e < end; e += 64) {
            int s = esrc[e];
            bool ok = (unsigned)s < (unsigned)N;
            float4 a = ok ? as4[s] : make_float4(-1e30f, -1e30f, -1e30f, -1e30f);
            float v0 = a.x + adn.x; v0 = v0 >= 0.f ? v0 : 0.2f * v0;
            float v1 = a.y + adn.y; v1 = v1 >= 0.f ? v1 : 0.2f * v1;
            float v2 = a.z + adn.z; v2 = v2 >= 0.f ? v2 : 0.2f * v2;
            float v3 = a.w + adn.w; v3 = v3 >= 0.f ? v3 : 0.2f * v3;
            float e0 = __expf(v0 - m0), e1 = __expf(v1 - m1);
            float e2 = __expf(v2 - m2), e3 = __expf(v3 - m3);
            s0 += e0; s1 += e1; s2 += e2; s3 += e3;
            if (fits) {
                int i = e - beg;
                srcS[w][i] = ok ? s : n;
                alphaS[w][0 * FCAPP + i] = e0;
                alphaS[w][1 * FCAPP + i] = e1;
                alphaS[w][2 * FCAPP + i] = e2;
                alphaS[w][3 * FCAPP + i] = e3;
            }
        }
        #pragma unroll
        for (int o = 1; o < 64; o <<= 1) {
            s0 += __shfl_xor(s0, o, 64); s1 += __shfl_xor(s1, o, 64);
            s2 += __shfl_xor(s2, o, 64); s3 += __shfl_xor(s3, o, 64);
        }
        float i0 = 1.f / (s0 + 1e-16f), i1 = 1.f / (s1 + 1e-16f);
        float i2 = 1.f / (s2 + 1e-16f), i3 = 1.f / (s3 + 1e-16f);
        float invH = hd == 0 ? i0 : hd == 1 ? i1 : hd == 2 ? i2 : i3;
        if (fits) {
            for (int i = 0; i < deg; i++) {
                int s = srcS[w][i];
                float wt = alphaS[w][hd * FCAPP + i];
                __hip_bfloat162 hv = h2[(size_t)s * 64 + lane];
                acc0 += wt * bf2f(hv.x);
                acc1 += wt * bf2f(hv.y);
            }
        } else {
            float mH  = hd == 0 ? m0 : hd == 1 ? m1 : hd == 2 ? m2 : m3;
            float adH = hd == 0 ? adn.x : hd == 1 ? adn.y : hd == 2 ? adn.z : adn.w;
            for (int e = beg; e < end; e++) {
                int s = esrc[e];
                if ((unsigned)s >= (unsigned)N) continue;
                float4 a = as4[s];
                float aH = hd == 0 ? a.x : hd == 1 ? a.y : hd == 2 ? a.z : a.w;
                float v = aH + adH; v = v >= 0.f ? v : 0.2f * v;
                float wt = __expf(v - mH);
                __hip_bfloat162 hv = h2[(size_t)s * 64 + lane];
                acc0 += wt * bf2f(hv.x);
                acc1 += wt * bf2f(hv.y);
            }
        }
        acc0 *= invH; acc1 *= invH;
    }
    acc0 += __shfl_xor(acc0, 16, 64); acc0 += __shfl_xor(acc0, 32, 64);
    acc1 += __shfl_xor(acc1, 16, 64); acc1 += __shfl_xor(acc1, 32, 64);
    if (lane < 16) {
        float o0 = acc0 * 0.25f + bias[2 * lane];     o0 = o0 >= 0.f ? o0 : 0.01f * o0;
        float o1 = acc1 * 0.25f + bias[2 * lane + 1]; o1 = o1 >= 0.f ? o1 : 0.01f * o1;
        ((float2*)xout)[(size_t)n * 16 + lane] = make_float2(o0, o1);
    }
}

// ---------------- MLP + output scatter (unchanged) --------------------------

__global__ __launch_bounds__(128) void k_mlp(
    const float* __restrict__ xF, const float* __restrict__ x3,
    const float* __restrict__ mW1, const float* __restrict__ mb1,
    const float* __restrict__ mW2, const float* __restrict__ mb2,
    const float* __restrict__ mW3, const float* __restrict__ mb3,
    const float* __restrict__ mW4, const float* __restrict__ mb4,
    const float* __restrict__ mW5, const float* __restrict__ mb5,
    const int* __restrict__ smask, const int* __restrict__ totals,
    const int* __restrict__ flag, int N, void* __restrict__ out) {
    __shared__ float W1[35 * 32], W2[1024], W3[1024], W4[1024], W5[32 * 12];
    __shared__ float B1[32], B2[32], B3[32], B4[32], B5[12];
    __shared__ float actA[35 * 128];
    __shared__ float actB[32 * 128];
    int t = threadIdx.x;
    for (int i = t; i < 1120; i += 128) W1[i] = mW1[i];
    for (int i = t; i < 1024; i += 128) { W2[i] = mW2[i]; W3[i] = mW3[i]; W4[i] = mW4[i]; }
    for (int i = t; i < 384; i += 128) W5[i] = mW5[i];
    if (t < 32) { B1[t] = mb1[t]; B2[t] = mb2[t]; B3[t] = mb3[t]; B4[t] = mb4[t]; }
    if (t < 12) B5[t] = mb5[t];
    __syncthreads();

    int n = blockIdx.x * 128 + t;
    bool alive = (n < N);
    float x0 = 0.f;
    if (alive) {
        x0 = xF[n * 3 + 0];
        actA[0 * 128 + t] = x0;
        actA[1 * 128 + t] = xF[n * 3 + 1];
        actA[2 * 128 + t] = xF[n * 3 + 2];
        for (int i = 0; i < 32; i++) actA[(3 + i) * 128 + t] = x3[(size_t)n * 32 + i];
    }

    float acc[32];

    #pragma unroll
    for (int o = 0; o < 32; o++) acc[o] = B1[o];
    #pragma unroll 2
    for (int i = 0; i < 35; i++) {
        float ai = actA[i * 128 + t];
        const float4* w4 = (const float4*)&W1[i * 32];
        #pragma unroll
        for (int q = 0; q < 8; q++) {
            float4 w = w4[q];
            acc[q*4+0] += ai * w.x; acc[q*4+1] += ai * w.y;
            acc[q*4+2] += ai * w.z; acc[q*4+3] += ai * w.w;
        }
    }
    #pragma unroll
    for (int o = 0; o < 32; o++) { float v = acc[o]; actB[o * 128 + t] = (v >= 0.f ? v : 0.01f * v); }

    #pragma unroll
    for (int o = 0; o < 32; o++) acc[o] = B2[o];
    #pragma unroll 2
    for (int i = 0; i < 32; i++) {
        float ai = actB[i * 128 + t];
        const float4* w4 = (const float4*)&W2[i * 32];
        #pragma unroll
        for (int q = 0; q < 8; q++) {
            float4 w = w4[q];
            acc[q*4+0] += ai * w.x; acc[q*4+1] += ai * w.y;
            acc[q*4+2] += ai * w.z; acc[q*4+3] += ai * w.w;
        }
    }
    #pragma unroll
    for (int o = 0; o < 32; o++) { float v = acc[o]; actA[o * 128 + t] = (v >= 0.f ? v : 0.01f * v); }

    #pragma unroll
    for (int o = 0; o < 32; o++) acc[o] = B3[o];
    #pragma unroll 2
    for (int i = 0; i < 32; i++) {
        float ai = actA[i * 128 + t];
        const float4* w4 = (const float4*)&W3[i * 32];
        #pragma unroll
        for (int q = 0; q < 8; q++) {
            float4 w = w4[q];
            acc[q*4+0] += ai * w.x; acc[q*4+1] += ai * w.y;
            acc[q*4+2] += ai * w.z; acc[q*4+3] += ai * w.w;
        }
    }
    #pragma unroll
    for (int o = 0; o < 32; o++) { float v = acc[o]; actB[o * 128 + t] = (v >= 0.f ? v : 0.01f * v); }

    #pragma unroll
    for (int o = 0; o < 32; o++) acc[o] = B4[o];
    #pragma unroll 2
    for (int i = 0; i < 32; i++) {
        float ai = actB[i * 128 + t];
        const float4* w4 = (const float4*)&W4[i * 32];
        #pragma unroll
        for (int q = 0; q < 8; q++) {
            float4 w = w4[q];
            acc[q*4+0] += ai * w.x; acc[q*4+1] += ai * w.y;
            acc[q*4+2] += ai * w.z; acc[q*4+3] += ai * w.w;
        }
    }
    #pragma unroll
    for (int o = 0; o < 32; o++) { float v = acc[o]; actA[o * 128 + t] = (v >= 0.f ? v : 0.01f * v); }

    float d[12];
    #pragma unroll
    for (int o = 0; o < 12; o++) d[o] = B5[o];
    #pragma unroll 2
    for (int i = 0; i < 32; i++) {
        float ai = actA[i * 128 + t];
        const float4* w4 = (const float4*)&W5[i * 12];
        #pragma unroll
        for (int q = 0; q < 3; q++) {
            float4 w = w4[q];
            d[q*4+0] += ai * w.x; d[q*4+1] += ai * w.y;
            d[q*4+2] += ai * w.z; d[q*4+3] += ai * w.w;
        }
    }
    if (!alive) return;
    #pragma unroll
    for (int o = 0; o < 12; o++) if (!(d[o] == d[o])) d[o] = 0.f;  // NaN scrub

    bool tower = (x0 == 0.0f);
    int r = smask[n];
    int Nt = *totals;
    int f32o = *flag;
    int base9, base3, rr;
    if (tower) { rr = r;     base9 = 0;      base3 = 9 * N; }
    else       { rr = n - r; base9 = 9 * Nt; base3 = 9 * N + 3 * Nt; }
    if (f32o) {
        float* o = (float*)out;
        #pragma unroll
        for (int j = 0; j < 9; j++) o[base9 + rr * 9 + j] = d[j];
        #pragma unroll
        for (int j = 0; j < 3; j++) o[base3 + rr * 3 + j] = d[9 + j];
    } else {
        __hip_bfloat16* o = (__hip_bfloat16*)out;
        #pragma unroll
        for (int j = 0; j < 9; j++) o[base9 + rr * 9 + j] = __float2bfloat16(d[j]);
        #pragma unroll
        for (int j = 0; j < 3; j++) o[base3 + rr * 3 + j] = __float2bfloat16(d[9 + j]);
    }
}

// ---------------- launch ----------------

extern "C" void kernel_launch(void* const* d_in, const int* in_sizes, int n_in,
                              void* d_out, int out_size, void* d_ws, size_t ws_size,
                              hipStream_t stream) {
    const void* xraw = d_in[0];
    const int*  eidx = (const int*)d_in[1];
    // d_in[2] edge_attr: unused

    int N  = in_sizes[0] / 3;
    int E  = in_sizes[1] / 2;
    int EE = E + N;

    Segs segs;
    int coff[22];
    int canonN = 3 * N;
    for (int i = 3; i <= 24; i++) {
        int a = i - 3;
        segs.s[a].src = d_in[i];
        segs.s[a].off = canonN;
        segs.s[a].len = in_sizes[i];
        coff[a] = canonN;
        canonN += in_sizes[i];
    }

    auto alignv = [](size_t v, size_t a) { return (v + a - 1) & ~(a - 1); };
    char* base = (char*)d_ws;
    size_t o = 0;
    float* canon = (float*)(base + o); o = alignv(o + (size_t)canonN * 4, 16);
    int* flag     = (int*)(base + o); o = alignv(o + 16, 16);
    ull* partials = (ull*)(base + o); o = alignv(o + 1024 * 8, 16);
    int* totals   = (int*)(base + o); o = alignv(o + 16, 16);
    int* off      = (int*)(base + o); o = alignv(o + (size_t)(N + 1) * 4, 16);
    int* cnt      = (int*)(base + o); o = alignv(o + (size_t)N * 4, 16);
    int* esrc     = (int*)(base + o); o = alignv(o + (size_t)EE * 4, 16);
    int* rank     = (int*)(base + o); o = alignv(o + (size_t)E * 4, 16);
    int* msk      = (int*)(base + o); o = alignv(o + (size_t)N * 4, 256);
    __hip_bfloat162* h2 = (__hip_bfloat162*)(base + o); o = alignv(o + (size_t)N * 64 * 4, 16);
    float* xb  = (float*)(base + o); o = alignv(o + (size_t)N * 32 * 4, 16);
    float* as_ = (float*)(base + o); o = alignv(o + (size_t)N * 16, 16);
    float* ad_ = (float*)(base + o);

    int nb = (N + 1023) / 1024;
    int g4 = (N + 3) / 4;
    int g64 = (N + 63) / 64;
    int gM = (N + 127) / 128;
    int gfill = (EE + 255) / 256;

    int nprobe = in_sizes[0] < 4096 ? in_sizes[0] : 4096;
    hipMemsetAsync(cnt, 0, (size_t)N * 4, stream);
    k_fused<<<86 + (E + 255) / 256, 256, 0, stream>>>(xraw, 3 * N, nprobe, segs, canon,
                                                      flag, eidx, E, N, cnt, msk, rank);
    k_scan_partial64<<<nb, 256, 0, stream>>>(cnt, msk, N, partials);
    k_scan_final64<<<nb, 256, 0, stream>>>(cnt, msk, N, partials, nb, off, off + N, totals);

    float* xF = canon;
    const float* W1  = canon + coff[0];  const float* aS1 = canon + coff[1];
    const float* aD1 = canon + coff[2];  const float* b1  = canon + coff[3];
    const float* W2  = canon + coff[4];  const float* aS2 = canon + coff[5];
    const float* aD2 = canon + coff[6];  const float* b2  = canon + coff[7];
    const float* W3  = canon + coff[8];  const float* aS3 = canon + coff[9];
    const float* aD3 = canon + coff[10]; const float* b3  = canon + coff[11];

    k_fill_node1<<<gfill + g64, 256, 0, stream>>>(eidx, rank, E, N, off, esrc,
                                                  xF, W1, aS1, aD1, h2, as_, ad_, gfill);
    k_edge<<<g4, 256, 0, stream>>>(h2, as_, ad_, off, esrc, b1, N, xb);
    k_node_mid<<<g64, 256, 0, stream>>>(xb, W2, aS2, aD2, N, h2, as_, ad_);
    k_edge<<<g4, 256, 0, stream>>>(h2, as_, ad_, off, esrc, b2, N, xb);
    k_node_mid<<<g64, 256, 0, stream>>>(xb, W3, aS3, aD3, N, h2, as_, ad_);
    k_edge<<<g4, 256, 0, stream>>>(h2, as_, ad_, off, esrc, b3, N, xb);

    k_mlp<<<gM, 128, 0, stream>>>(xF, xb,
        canon + coff[12], canon + coff[13], canon + coff[14], canon + coff[15],
        canon + coff[16], canon + coff[17], canon + coff[18], canon + coff[19],
        canon + coff[20], canon + coff[21], msk, totals, flag, N, d_out);
}

// Round 14
// 437.336 us; speedup vs baseline: 1.4387x; 1.4387x over previous
//
#include <hip/hip_runtime.h>
#include <hip/hip_bf16.h>

#define DEV __device__ __forceinline__

DEV float bf2f(__hip_bfloat16 v) { return __bfloat162float(v); }

typedef unsigned long long ull;

// ---------------- fused ingest + tower mask + degree count (+rank) ----------
struct Seg  { const void* src; int off; int len; };
struct Segs { Seg s[22]; };

__global__ void k_fused(const void* xsrc, int nx3, int nprobe, Segs segs,
                        float* canon, int* flag, const int* eidx, int E, int N,
                        int* cnt, int* msk, int* rank) {
    __shared__ int red[256];
    int t = threadIdx.x, b = blockIdx.x;
    const unsigned short* xr = (const unsigned short*)xsrc;
    int bad = 0;
    for (int j = t; j < nprobe; j += 256) {
        unsigned e = (xr[j] >> 7) & 0xFF;
        if (e >= 0x8F) bad++;    // |v| >= 2^16: impossible for true bf16 N(0,1)
    }
    red[t] = bad; __syncthreads();
    for (int o = 128; o > 0; o >>= 1) { if (t < o) red[t] += red[t + o]; __syncthreads(); }
    int f32 = (red[0] > 256) ? 1 : 0;
    if (b == 0 && t == 0) flag[0] = f32;

    if (b < 64) {
        for (int i = b * 256 + t; i < nx3; i += 64 * 256) {
            float v = f32 ? ((const float*)xsrc)[i] : bf2f(((const __hip_bfloat16*)xsrc)[i]);
            if (!(v == v) || fabsf(v) > 1e30f) v = 0.f;   // scrub
            canon[i] = v;
            if (i % 3 == 0) msk[i / 3] = (v == 0.0f) ? 1 : 0;
        }
    } else if (b < 86) {
        Seg sg = segs.s[b - 64];
        for (int i = t; i < sg.len; i += 256) {
            float v = f32 ? ((const float*)sg.src)[i] : bf2f(((const __hip_bfloat16*)sg.src)[i]);
            if (!(v == v) || fabsf(v) > 1e30f) v = 0.f;
            canon[sg.off + i] = v;
        }
    } else {
        int e = (b - 86) * 256 + t;
        if (e < E) {
            int d = eidx[E + e];
            if ((unsigned)d < (unsigned)N) {
                int p = atomicAdd(&cnt[d], 1);
                rank[e] = p;        // rank within dst bucket -> atomic-free fill
            }
        }
    }
}

// ---------------- packed 64-bit exclusive scan ------------------------------

DEV ull packval(const int* cnt, const int* msk, int i) {
    return ((ull)(unsigned)msk[i] << 32) | (unsigned)(cnt[i] + 1);
}

__global__ void k_scan_partial64(const int* __restrict__ cnt, const int* __restrict__ msk,
                                 int n, ull* __restrict__ partials) {
    __shared__ ull red[256];
    int t = threadIdx.x, b = blockIdx.x;
    int base = b * 1024 + t * 4;
    ull s = 0;
    #pragma unroll
    for (int j = 0; j < 4; j++) { int i = base + j; if (i < n) s += packval(cnt, msk, i); }
    red[t] = s; __syncthreads();
    for (int o = 128; o > 0; o >>= 1) { if (t < o) red[t] += red[t + o]; __syncthreads(); }
    if (t == 0) partials[b] = red[0];
}

__global__ void k_scan_final64(const int* __restrict__ cnt, int* __restrict__ msk, int n,
                               const ull* __restrict__ partials, int nb,
                               int* __restrict__ off, int* __restrict__ offN,
                               int* __restrict__ totals) {
    __shared__ ull sums[256];
    __shared__ ull redLT[256], redALL[256];
    int t = threadIdx.x, b = blockIdx.x;

    ull sLT = 0, sALL = 0;
    for (int i = t; i < nb; i += 256) {
        ull v = partials[i];
        sALL += v;
        if (i < b) sLT += v;
    }
    redLT[t] = sLT; redALL[t] = sALL; __syncthreads();
    for (int o = 128; o > 0; o >>= 1) {
        if (t < o) { redLT[t] += redLT[t + o]; redALL[t] += redALL[t + o]; }
        __syncthreads();
    }
    ull blockbase = redLT[0];
    if (b == 0 && t == 0) {
        ull tot = redALL[0];
        *offN = (int)(tot & 0xffffffffu);
        *totals = (int)(tot >> 32);
    }
    __syncthreads();

    int base = b * 1024 + t * 4;
    ull v0 = 0, v1 = 0, v2 = 0, v3 = 0;
    if (base     < n) v0 = packval(cnt, msk, base);
    if (base + 1 < n) v1 = packval(cnt, msk, base + 1);
    if (base + 2 < n) v2 = packval(cnt, msk, base + 2);
    if (base + 3 < n) v3 = packval(cnt, msk, base + 3);
    ull s = v0 + v1 + v2 + v3;
    sums[t] = s; __syncthreads();
    for (int o = 1; o < 256; o <<= 1) {
        ull x = (t >= o) ? sums[t - o] : 0;
        __syncthreads();
        sums[t] += x;
        __syncthreads();
    }
    ull run = blockbase + (sums[t] - s);
    #pragma unroll
    for (int j = 0; j < 4; j++) {
        int i = base + j;
        if (i < n) {
            off[i] = (int)(run & 0xffffffffu);
            msk[i] = (int)(run >> 32);
            run += (j == 0 ? v0 : j == 1 ? v1 : j == 2 ? v2 : v3);
        }
    }
}

// ---------------- fused CSR fill (atomic-free) + GAT layer-1 node -----------

__global__ __launch_bounds__(256) void k_fill_node1(
    const int* __restrict__ eidx, const int* __restrict__ rank, int E, int N,
    const int* __restrict__ off, int* __restrict__ esrc,
    const float* __restrict__ xF, const float* __restrict__ W,
    const float* __restrict__ atS, const float* __restrict__ atD,
    __hip_bfloat162* __restrict__ h2, float* __restrict__ as_, float* __restrict__ ad_,
    int gfill) {
    __shared__ float xl[64 * 4];
    int b = blockIdx.x;
    if (b < gfill) {
        int e = b * 256 + threadIdx.x;
        if (e < E) {
            int s = eidx[e], d = eidx[E + e];
            if ((unsigned)d < (unsigned)N && (unsigned)s < (unsigned)N)
                esrc[off[d] + rank[e]] = s;
        } else if (e < E + N) {
            int i = e - E;
            esrc[off[i + 1] - 1] = i;   // self-loop in the last slot
        }
        return;
    }
    int t = threadIdx.x, lane = t & 63, w = t >> 6;
    int nblk = (b - gfill) * 64;
    int cnt = N - nblk; if (cnt > 64) cnt = 64;

    if (t < 64) xl[t * 4 + 3] = 0.f;
    for (int i = t; i < cnt * 3; i += 256) xl[(i / 3) * 4 + (i % 3)] = xF[(size_t)nblk * 3 + i];

    const float2* W2 = (const float2*)W;
    float2 Wr0 = W2[0 * 64 + lane], Wr1 = W2[1 * 64 + lane], Wr2 = W2[2 * 64 + lane];
    float2 aSp = ((const float2*)atS)[lane];
    float2 aDp = ((const float2*)atD)[lane];
    int hd = lane >> 4;
    __syncthreads();

    for (int i = 0; i < 16; i++) {
        int n = nblk + w * 16 + i;
        if (n >= N) break;
        float4 xv = ((const float4*)xl)[w * 16 + i];
        float acc0 = xv.x * Wr0.x + xv.y * Wr1.x + xv.z * Wr2.x;
        float acc1 = xv.x * Wr0.y + xv.y * Wr1.y + xv.z * Wr2.y;
        __hip_bfloat162 hv; hv.x = __float2bfloat16(acc0); hv.y = __float2bfloat16(acc1);
        h2[(size_t)n * 64 + lane] = hv;
        float p = acc0 * aSp.x + acc1 * aSp.y;
        float q = acc0 * aDp.x + acc1 * aDp.y;
        #pragma unroll
        for (int o = 1; o < 16; o <<= 1) { p += __shfl_xor(p, o, 64); q += __shfl_xor(q, o, 64); }
        if ((lane & 15) == 0) { as_[n * 4 + hd] = p; ad_[n * 4 + hd] = q; }
    }
}

// ---------------- GAT node kernel (layers 2,3) ------------------------------

__global__ __launch_bounds__(256) void k_node_mid(
    const float* __restrict__ xin, const float* __restrict__ W,
    const float* __restrict__ atS, const float* __restrict__ atD,
    int N, __hip_bfloat162* __restrict__ h2, float* __restrict__ as_, float* __restrict__ ad_) {
    __shared__ float xl[64 * 32];
    int t = threadIdx.x, lane = t & 63, w = t >> 6;
    int nblk = blockIdx.x * 64;
    int cnt = N - nblk; if (cnt > 64) cnt = 64;

    {
        const float4* g4 = (const float4*)(xin + (size_t)nblk * 32);
        float4* l4 = (float4*)xl;
        int lim = cnt * 8;
        if (t < lim) l4[t] = g4[t];
        int t2 = t + 256;
        if (t2 < lim) l4[t2] = g4[t2];
    }

    const float2* W2 = (const float2*)W;
    float2 Wr[32];
    #pragma unroll
    for (int k = 0; k < 32; k++) Wr[k] = W2[k * 64 + lane];
    float2 aSp = ((const float2*)atS)[lane];
    float2 aDp = ((const float2*)atD)[lane];
    int hd = lane >> 4;
    __syncthreads();

    for (int i = 0; i < 16; i++) {
        int n = nblk + w * 16 + i;
        if (n >= N) break;
        const float4* xv4 = (const float4*)&xl[(w * 16 + i) * 32];
        float acc0 = 0.f, acc1 = 0.f;
        #pragma unroll
        for (int kk = 0; kk < 8; kk++) {
            float4 xv = xv4[kk];
            acc0 += xv.x * Wr[4*kk+0].x; acc1 += xv.x * Wr[4*kk+0].y;
            acc0 += xv.y * Wr[4*kk+1].x; acc1 += xv.y * Wr[4*kk+1].y;
            acc0 += xv.z * Wr[4*kk+2].x; acc1 += xv.z * Wr[4*kk+2].y;
            acc0 += xv.w * Wr[4*kk+3].x; acc1 += xv.w * Wr[4*kk+3].y;
        }
        __hip_bfloat162 hv; hv.x = __float2bfloat16(acc0); hv.y = __float2bfloat16(acc1);
        h2[(size_t)n * 64 + lane] = hv;
        float p = acc0 * aSp.x + acc1 * aSp.y;
        float q = acc0 * aDp.x + acc1 * aDp.y;
        #pragma unroll
        for (int o = 1; o < 16; o <<= 1) { p += __shfl_xor(p, o, 64); q += __shfl_xor(q, o, 64); }
        if ((lane & 15) == 0) { as_[n * 4 + hd] = p; ad_[n * 4 + hd] = q; }
    }
}

// ---------------- GAT edge kernel -------------------------------------------
// Round-14 fast path: round-11's scoring (1 score/lane + butterflies — cheap)
// but the per-chunk weight/src extraction goes through a per-wave LDS stash:
// each lane writes ex once (<=2-way bank alias = free), gather reads one
// group-uniform ds_read_b128 (weights) + one wave-uniform int4 (srcs) per
// chunk. LDS-pipe ops/node: ~33 -> ~19, zero added VALU (round-13's mistake
// was replacing bpermutes with redundant per-lane VALU+loads: 56->121 us).
// Same-wave LDS RAW needs no barrier. Fast-path stash stride 20 floats:
// head bases 0/20/40/60 -> byte offsets 0/80/160/240 (16B-aligned), first
// banks {0,20,8,28}+4c -> the 4 head groups hit disjoint bank quads.

constexpr int FCAP  = 64;
constexpr int FCAPP = 68;

__global__ __launch_bounds__(256) void k_edge(
    const __hip_bfloat162* __restrict__ h2, const float* __restrict__ as_,
    const float* __restrict__ ad_, const int* __restrict__ off,
    const int* __restrict__ esrc, const float* __restrict__ bias,
    int N, float* __restrict__ xout) {
    __shared__ __align__(16) float alphaS[4][4 * FCAPP];
    __shared__ __align__(16) int   srcS[4][FCAP];
    int t = threadIdx.x, lane = t & 63, w = t >> 6;
    int n = blockIdx.x * 4 + w;
    if (n >= N) return;
    int beg = off[n], end = off[n + 1];
    int deg = end - beg;
    float4 adn = ((const float4*)ad_)[n];
    const float4* as4 = (const float4*)as_;
    int hd = lane >> 4;

    float acc0 = 0.f, acc1 = 0.f;

    if (deg <= 16) {
        int e = lane >> 2, h = lane & 3;
        int s_e = n;
        float v = -1e30f;
        if (e < deg) {
            int s = esrc[beg + e];
            if ((unsigned)s < (unsigned)N) {
                s_e = s;
                float asv = as_[s * 4 + h];
                float adv = h == 0 ? adn.x : h == 1 ? adn.y : h == 2 ? adn.z : adn.w;
                v = asv + adv; v = v >= 0.f ? v : 0.2f * v;
            }
        }
        float m = v;
        #pragma unroll
        for (int o = 4; o < 64; o <<= 1) m = fmaxf(m, __shfl_xor(m, o, 64));
        float ex = (v > -1e29f) ? __expf(v - m) : 0.f;   // pad/invalid -> 0
        float ssum = ex;
        #pragma unroll
        for (int o = 4; o < 64; o <<= 1) ssum += __shfl_xor(ssum, o, 64);
        float inv = 1.f / (ssum + 1e-16f);
        float invH = __shfl(inv, hd, 64);

        // stash numerators + srcs in per-wave LDS (same-wave RAW, no barrier)
        alphaS[w][h * 20 + e] = ex;
        if (h == 0) srcS[w][e] = s_e;

        #pragma unroll
        for (int c = 0; c < 4; c++) {
            if (4 * c < deg) {
                float4 wt4 = *(const float4*)&alphaS[w][hd * 20 + 4 * c];
                int4   s4  = *(const int4*)&srcS[w][4 * c];
                __hip_bfloat162 g0 = h2[(size_t)s4.x * 64 + lane];
                __hip_bfloat162 g1 = h2[(size_t)s4.y * 64 + lane];
                __hip_bfloat162 g2 = h2[(size_t)s4.z * 64 + lane];
                __hip_bfloat162 g3 = h2[(size_t)s4.w * 64 + lane];
                acc0 += wt4.x * bf2f(g0.x) + wt4.y * bf2f(g1.x)
                      + wt4.z * bf2f(g2.x) + wt4.w * bf2f(g3.x);
                acc1 += wt4.x * bf2f(g0.y) + wt4.y * bf2f(g1.y)
                      + wt4.z * bf2f(g2.y) + wt4.w * bf2f(g3.y);
            }
        }
        acc0 *= invH; acc1 *= invH;
    } else {
        bool fits = (deg <= FCAP);
        float m0 = -1e30f, m1 = -1e30f, m2 = -1e30f, m3 = -1e30f;
        for (int e = beg + lane; e < end; e += 64) {
            int s = esrc[e];
            if ((unsigned)s >= (unsigned)N) continue;
            float4 a = as4[s];
            float v0 = a.x + adn.x; v0 = v0 >= 0.f ? v0 : 0.2f * v0;
            float v1 = a.y + adn.y; v1 = v1 >= 0.f ? v1 : 0.2f * v1;
            float v2 = a.z + adn.z; v2 = v2 >= 0.f ? v2 : 0.2f * v2;
            float v3 = a.w + adn.w; v3 = v3 >= 0.f ? v3 : 0.2f * v3;
            m0 = fmaxf(m0, v0); m1 = fmaxf(m1, v1); m2 = fmaxf(m2, v2); m3 = fmaxf(m3, v3);
        }
        #pragma unroll
        for (int o = 1; o < 64; o <<= 1) {
            m0 = fmaxf(m0, __shfl_xor(m0, o, 64));
            m1 = fmaxf(m1, __shfl_xor(m1, o, 64));
            m2 = fmaxf(m2, __shfl_xor(m2, o, 64));
            m3 = fmaxf(m3, __shfl_xor(m3, o, 64));
        }
        float s0 = 0.f, s1 = 0.f, s2 = 0.f, s3 = 0.f;
        for (int e = beg + lane; e < end; e += 64) {
            int s = esrc[e];
            bool ok = (unsigned)s < (unsigned)N;
            float4 a = ok ? as4[s] : make_float4(-1e30f, -1e30f, -1e30f, -1e30f);
            float v0 = a.x + adn.x; v0 = v0 >= 0.f ? v0 : 0.2f * v0;
            float v1 = a.y + adn.y; v1 = v1 >= 0.f ? v1 : 0.2f * v1;
            float v2 = a.z + adn.z; v2 = v2 >= 0.f ? v2 : 0.2f * v2;
            float v3 = a.w + adn.w; v3 = v3 >= 0.f ? v3 : 0.2f * v3;
            float e0 = __expf(v0 - m0), e1 = __expf(v1 - m1);
            float e2 = __expf(v2 - m2), e3 = __expf(v3 - m3);
            s0 += e0; s1 += e1; s2 += e2; s3 += e3;
            if (fits) {
                int i = e - beg;
                srcS[w][i] = ok ? s : n;
                alphaS[w][0 * FCAPP + i] = e0;
                alphaS[w][1 * FCAPP + i] = e1;
                alphaS[w][2 * FCAPP + i] = e2;
                alphaS[w][3 * FCAPP + i] = e3;
            }
        }
        #pragma unroll
        for (int o = 1; o < 64; o <<= 1) {
            s0 += __shfl_xor(s0, o, 64); s1 += __shfl_xor(s1, o, 64);
            s2 += __shfl_xor(s2, o, 64); s3 += __shfl_xor(s3, o, 64);
        }
        float i0 = 1.f / (s0 + 1e-16f), i1 = 1.f / (s1 + 1e-16f);
        float i2 = 1.f / (s2 + 1e-16f), i3 = 1.f / (s3 + 1e-16f);
        float invH = hd == 0 ? i0 : hd == 1 ? i1 : hd == 2 ? i2 : i3;
        if (fits) {
            for (int i = 0; i < deg; i++) {
                int s = srcS[w][i];
                float wt = alphaS[w][hd * FCAPP + i];
                __hip_bfloat162 hv = h2[(size_t)s * 64 + lane];
                acc0 += wt * bf2f(hv.x);
                acc1 += wt * bf2f(hv.y);
            }
        } else {
            float mH  = hd == 0 ? m0 : hd == 1 ? m1 : hd == 2 ? m2 : m3;
            float adH = hd == 0 ? adn.x : hd == 1 ? adn.y : hd == 2 ? adn.z : adn.w;
            for (int e = beg; e < end; e++) {
                int s = esrc[e];
                if ((unsigned)s >= (unsigned)N) continue;
                float4 a = as4[s];
                float aH = hd == 0 ? a.x : hd == 1 ? a.y : hd == 2 ? a.z : a.w;
                float v = aH + adH; v = v >= 0.f ? v : 0.2f * v;
                float wt = __expf(v - mH);
                __hip_bfloat162 hv = h2[(size_t)s * 64 + lane];
                acc0 += wt * bf2f(hv.x);
                acc1 += wt * bf2f(hv.y);
            }
        }
        acc0 *= invH; acc1 *= invH;
    }
    acc0 += __shfl_xor(acc0, 16, 64); acc0 += __shfl_xor(acc0, 32, 64);
    acc1 += __shfl_xor(acc1, 16, 64); acc1 += __shfl_xor(acc1, 32, 64);
    if (lane < 16) {
        float o0 = acc0 * 0.25f + bias[2 * lane];     o0 = o0 >= 0.f ? o0 : 0.01f * o0;
        float o1 = acc1 * 0.25f + bias[2 * lane + 1]; o1 = o1 >= 0.f ? o1 : 0.01f * o1;
        ((float2*)xout)[(size_t)n * 16 + lane] = make_float2(o0, o1);
    }
}

// ---------------- MLP + output scatter (unchanged) --------------------------

__global__ __launch_bounds__(128) void k_mlp(
    const float* __restrict__ xF, const float* __restrict__ x3,
    const float* __restrict__ mW1, const float* __restrict__ mb1,
    const float* __restrict__ mW2, const float* __restrict__ mb2,
    const float* __restrict__ mW3, const float* __restrict__ mb3,
    const float* __restrict__ mW4, const float* __restrict__ mb4,
    const float* __restrict__ mW5, const float* __restrict__ mb5,
    const int* __restrict__ smask, const int* __restrict__ totals,
    const int* __restrict__ flag, int N, void* __restrict__ out) {
    __shared__ float W1[35 * 32], W2[1024], W3[1024], W4[1024], W5[32 * 12];
    __shared__ float B1[32], B2[32], B3[32], B4[32], B5[12];
    __shared__ float actA[35 * 128];
    __shared__ float actB[32 * 128];
    int t = threadIdx.x;
    for (int i = t; i < 1120; i += 128) W1[i] = mW1[i];
    for (int i = t; i < 1024; i += 128) { W2[i] = mW2[i]; W3[i] = mW3[i]; W4[i] = mW4[i]; }
    for (int i = t; i < 384; i += 128) W5[i] = mW5[i];
    if (t < 32) { B1[t] = mb1[t]; B2[t] = mb2[t]; B3[t] = mb3[t]; B4[t] = mb4[t]; }
    if (t < 12) B5[t] = mb5[t];
    __syncthreads();

    int n = blockIdx.x * 128 + t;
    bool alive = (n < N);
    float x0 = 0.f;
    if (alive) {
        x0 = xF[n * 3 + 0];
        actA[0 * 128 + t] = x0;
        actA[1 * 128 + t] = xF[n * 3 + 1];
        actA[2 * 128 + t] = xF[n * 3 + 2];
        for (int i = 0; i < 32; i++) actA[(3 + i) * 128 + t] = x3[(size_t)n * 32 + i];
    }

    float acc[32];

    #pragma unroll
    for (int o = 0; o < 32; o++) acc[o] = B1[o];
    #pragma unroll 2
    for (int i = 0; i < 35; i++) {
        float ai = actA[i * 128 + t];
        const float4* w4 = (const float4*)&W1[i * 32];
        #pragma unroll
        for (int q = 0; q < 8; q++) {
            float4 w = w4[q];
            acc[q*4+0] += ai * w.x; acc[q*4+1] += ai * w.y;
            acc[q*4+2] += ai * w.z; acc[q*4+3] += ai * w.w;
        }
    }
    #pragma unroll
    for (int o = 0; o < 32; o++) { float v = acc[o]; actB[o * 128 + t] = (v >= 0.f ? v : 0.01f * v); }

    #pragma unroll
    for (int o = 0; o < 32; o++) acc[o] = B2[o];
    #pragma unroll 2
    for (int i = 0; i < 32; i++) {
        float ai = actB[i * 128 + t];
        const float4* w4 = (const float4*)&W2[i * 32];
        #pragma unroll
        for (int q = 0; q < 8; q++) {
            float4 w = w4[q];
            acc[q*4+0] += ai * w.x; acc[q*4+1] += ai * w.y;
            acc[q*4+2] += ai * w.z; acc[q*4+3] += ai * w.w;
        }
    }
    #pragma unroll
    for (int o = 0; o < 32; o++) { float v = acc[o]; actA[o * 128 + t] = (v >= 0.f ? v : 0.01f * v); }

    #pragma unroll
    for (int o = 0; o < 32; o++) acc[o] = B3[o];
    #pragma unroll 2
    for (int i = 0; i < 32; i++) {
        float ai = actA[i * 128 + t];
        const float4* w4 = (const float4*)&W3[i * 32];
        #pragma unroll
        for (int q = 0; q < 8; q++) {
            float4 w = w4[q];
            acc[q*4+0] += ai * w.x; acc[q*4+1] += ai * w.y;
            acc[q*4+2] += ai * w.z; acc[q*4+3] += ai * w.w;
        }
    }
    #pragma unroll
    for (int o = 0; o < 32; o++) { float v = acc[o]; actB[o * 128 + t] = (v >= 0.f ? v : 0.01f * v); }

    #pragma unroll
    for (int o = 0; o < 32; o++) acc[o] = B4[o];
    #pragma unroll 2
    for (int i = 0; i < 32; i++) {
        float ai = actB[i * 128 + t];
        const float4* w4 = (const float4*)&W4[i * 32];
        #pragma unroll
        for (int q = 0; q < 8; q++) {
            float4 w = w4[q];
            acc[q*4+0] += ai * w.x; acc[q*4+1] += ai * w.y;
            acc[q*4+2] += ai * w.z; acc[q*4+3] += ai * w.w;
        }
    }
    #pragma unroll
    for (int o = 0; o < 32; o++) { float v = acc[o]; actA[o * 128 + t] = (v >= 0.f ? v : 0.01f * v); }

    float d[12];
    #pragma unroll
    for (int o = 0; o < 12; o++) d[o] = B5[o];
    #pragma unroll 2
    for (int i = 0; i < 32; i++) {
        float ai = actA[i * 128 + t];
        const float4* w4 = (const float4*)&W5[i * 12];
        #pragma unroll
        for (int q = 0; q < 3; q++) {
            float4 w = w4[q];
            d[q*4+0] += ai * w.x; d[q*4+1] += ai * w.y;
            d[q*4+2] += ai * w.z; d[q*4+3] += ai * w.w;
        }
    }
    if (!alive) return;
    #pragma unroll
    for (int o = 0; o < 12; o++) if (!(d[o] == d[o])) d[o] = 0.f;  // NaN scrub

    bool tower = (x0 == 0.0f);
    int r = smask[n];
    int Nt = *totals;
    int f32o = *flag;
    int base9, base3, rr;
    if (tower) { rr = r;     base9 = 0;      base3 = 9 * N; }
    else       { rr = n - r; base9 = 9 * Nt; base3 = 9 * N + 3 * Nt; }
    if (f32o) {
        float* o = (float*)out;
        #pragma unroll
        for (int j = 0; j < 9; j++) o[base9 + rr * 9 + j] = d[j];
        #pragma unroll
        for (int j = 0; j < 3; j++) o[base3 + rr * 3 + j] = d[9 + j];
    } else {
        __hip_bfloat16* o = (__hip_bfloat16*)out;
        #pragma unroll
        for (int j = 0; j < 9; j++) o[base9 + rr * 9 + j] = __float2bfloat16(d[j]);
        #pragma unroll
        for (int j = 0; j < 3; j++) o[base3 + rr * 3 + j] = __float2bfloat16(d[9 + j]);
    }
}

// ---------------- launch ----------------

extern "C" void kernel_launch(void* const* d_in, const int* in_sizes, int n_in,
                              void* d_out, int out_size, void* d_ws, size_t ws_size,
                              hipStream_t stream) {
    const void* xraw = d_in[0];
    const int*  eidx = (const int*)d_in[1];
    // d_in[2] edge_attr: unused

    int N  = in_sizes[0] / 3;
    int E  = in_sizes[1] / 2;
    int EE = E + N;

    Segs segs;
    int coff[22];
    int canonN = 3 * N;
    for (int i = 3; i <= 24; i++) {
        int a = i - 3;
        segs.s[a].src = d_in[i];
        segs.s[a].off = canonN;
        segs.s[a].len = in_sizes[i];
        coff[a] = canonN;
        canonN += in_sizes[i];
    }

    auto alignv = [](size_t v, size_t a) { return (v + a - 1) & ~(a - 1); };
    char* base = (char*)d_ws;
    size_t o = 0;
    float* canon = (float*)(base + o); o = alignv(o + (size_t)canonN * 4, 16);
    int* flag     = (int*)(base + o); o = alignv(o + 16, 16);
    ull* partials = (ull*)(base + o); o = alignv(o + 1024 * 8, 16);
    int* totals   = (int*)(base + o); o = alignv(o + 16, 16);
    int* off      = (int*)(base + o); o = alignv(o + (size_t)(N + 1) * 4, 16);
    int* cnt      = (int*)(base + o); o = alignv(o + (size_t)N * 4, 16);
    int* esrc     = (int*)(base + o); o = alignv(o + (size_t)EE * 4, 16);
    int* rank     = (int*)(base + o); o = alignv(o + (size_t)E * 4, 16);
    int* msk      = (int*)(base + o); o = alignv(o + (size_t)N * 4, 256);
    __hip_bfloat162* h2 = (__hip_bfloat162*)(base + o); o = alignv(o + (size_t)N * 64 * 4, 16);
    float* xb  = (float*)(base + o); o = alignv(o + (size_t)N * 32 * 4, 16);
    float* as_ = (float*)(base + o); o = alignv(o + (size_t)N * 16, 16);
    float* ad_ = (float*)(base + o);

    int nb = (N + 1023) / 1024;
    int g4 = (N + 3) / 4;
    int g64 = (N + 63) / 64;
    int gM = (N + 127) / 128;
    int gfill = (EE + 255) / 256;

    int nprobe = in_sizes[0] < 4096 ? in_sizes[0] : 4096;
    hipMemsetAsync(cnt, 0, (size_t)N * 4, stream);
    k_fused<<<86 + (E + 255) / 256, 256, 0, stream>>>(xraw, 3 * N, nprobe, segs, canon,
                                                      flag, eidx, E, N, cnt, msk, rank);
    k_scan_partial64<<<nb, 256, 0, stream>>>(cnt, msk, N, partials);
    k_scan_final64<<<nb, 256, 0, stream>>>(cnt, msk, N, partials, nb, off, off + N, totals);

    float* xF = canon;
    const float* W1  = canon + coff[0];  const float* aS1 = canon + coff[1];
    const float* aD1 = canon + coff[2];  const float* b1  = canon + coff[3];
    const float* W2  = canon + coff[4];  const float* aS2 = canon + coff[5];
    const float* aD2 = canon + coff[6];  const float* b2  = canon + coff[7];
    const float* W3  = canon + coff[8];  const float* aS3 = canon + coff[9];
    const float* aD3 = canon + coff[10]; const float* b3  = canon + coff[11];

    k_fill_node1<<<gfill + g64, 256, 0, stream>>>(eidx, rank, E, N, off, esrc,
                                                  xF, W1, aS1, aD1, h2, as_, ad_, gfill);
    k_edge<<<g4, 256, 0, stream>>>(h2, as_, ad_, off, esrc, b1, N, xb);
    k_node_mid<<<g64, 256, 0, stream>>>(xb, W2, aS2, aD2, N, h2, as_, ad_);
    k_edge<<<g4, 256, 0, stream>>>(h2, as_, ad_, off, esrc, b2, N, xb);
    k_node_mid<<<g64, 256, 0, stream>>>(xb, W3, aS3, aD3, N, h2, as_, ad_);
    k_edge<<<g4, 256, 0, stream>>>(h2, as_, ad_, off, esrc, b3, N, xb);

    k_mlp<<<gM, 128, 0, stream>>>(xF, xb,
        canon + coff[12], canon + coff[13], canon + coff[14], canon + coff[15],
        canon + coff[16], canon + coff[17], canon + coff[18], canon + coff[19],
        canon + coff[20], canon + coff[21], msk, totals, flag, N, d_out);
}

// Round 15
// 421.598 us; speedup vs baseline: 1.4924x; 1.0373x over previous
//
#include <hip/hip_runtime.h>
#include <hip/hip_bf16.h>

#define DEV __device__ __forceinline__

DEV float bf2f(__hip_bfloat16 v) { return __bfloat162float(v); }

typedef unsigned long long ull;

// ---------------- fused ingest + tower mask + degree count (+rank) ----------
struct Seg  { const void* src; int off; int len; };
struct Segs { Seg s[22]; };

__global__ void k_fused(const void* xsrc, int nx3, int nprobe, Segs segs,
                        float* canon, int* flag, const int* eidx, int E, int N,
                        int* cnt, int* msk, int* rank) {
    __shared__ int red[256];
    int t = threadIdx.x, b = blockIdx.x;
    const unsigned short* xr = (const unsigned short*)xsrc;
    int bad = 0;
    for (int j = t; j < nprobe; j += 256) {
        unsigned e = (xr[j] >> 7) & 0xFF;
        if (e >= 0x8F) bad++;    // |v| >= 2^16: impossible for true bf16 N(0,1)
    }
    red[t] = bad; __syncthreads();
    for (int o = 128; o > 0; o >>= 1) { if (t < o) red[t] += red[t + o]; __syncthreads(); }
    int f32 = (red[0] > 256) ? 1 : 0;
    if (b == 0 && t == 0) flag[0] = f32;

    if (b < 64) {
        for (int i = b * 256 + t; i < nx3; i += 64 * 256) {
            float v = f32 ? ((const float*)xsrc)[i] : bf2f(((const __hip_bfloat16*)xsrc)[i]);
            if (!(v == v) || fabsf(v) > 1e30f) v = 0.f;   // scrub
            canon[i] = v;
            if (i % 3 == 0) msk[i / 3] = (v == 0.0f) ? 1 : 0;
        }
    } else if (b < 86) {
        Seg sg = segs.s[b - 64];
        for (int i = t; i < sg.len; i += 256) {
            float v = f32 ? ((const float*)sg.src)[i] : bf2f(((const __hip_bfloat16*)sg.src)[i]);
            if (!(v == v) || fabsf(v) > 1e30f) v = 0.f;
            canon[sg.off + i] = v;
        }
    } else {
        int e = (b - 86) * 256 + t;
        if (e < E) {
            int d = eidx[E + e];
            if ((unsigned)d < (unsigned)N) {
                int p = atomicAdd(&cnt[d], 1);
                rank[e] = p;        // rank within dst bucket -> atomic-free fill
            }
        }
    }
}

// ---------------- packed 64-bit exclusive scan ------------------------------

DEV ull packval(const int* cnt, const int* msk, int i) {
    return ((ull)(unsigned)msk[i] << 32) | (unsigned)(cnt[i] + 1);
}

__global__ void k_scan_partial64(const int* __restrict__ cnt, const int* __restrict__ msk,
                                 int n, ull* __restrict__ partials) {
    __shared__ ull red[256];
    int t = threadIdx.x, b = blockIdx.x;
    int base = b * 1024 + t * 4;
    ull s = 0;
    #pragma unroll
    for (int j = 0; j < 4; j++) { int i = base + j; if (i < n) s += packval(cnt, msk, i); }
    red[t] = s; __syncthreads();
    for (int o = 128; o > 0; o >>= 1) { if (t < o) red[t] += red[t + o]; __syncthreads(); }
    if (t == 0) partials[b] = red[0];
}

__global__ void k_scan_final64(const int* __restrict__ cnt, int* __restrict__ msk, int n,
                               const ull* __restrict__ partials, int nb,
                               int* __restrict__ off, int* __restrict__ offN,
                               int* __restrict__ totals) {
    __shared__ ull sums[256];
    __shared__ ull redLT[256], redALL[256];
    int t = threadIdx.x, b = blockIdx.x;

    ull sLT = 0, sALL = 0;
    for (int i = t; i < nb; i += 256) {
        ull v = partials[i];
        sALL += v;
        if (i < b) sLT += v;
    }
    redLT[t] = sLT; redALL[t] = sALL; __syncthreads();
    for (int o = 128; o > 0; o >>= 1) {
        if (t < o) { redLT[t] += redLT[t + o]; redALL[t] += redALL[t + o]; }
        __syncthreads();
    }
    ull blockbase = redLT[0];
    if (b == 0 && t == 0) {
        ull tot = redALL[0];
        *offN = (int)(tot & 0xffffffffu);
        *totals = (int)(tot >> 32);
    }
    __syncthreads();

    int base = b * 1024 + t * 4;
    ull v0 = 0, v1 = 0, v2 = 0, v3 = 0;
    if (base     < n) v0 = packval(cnt, msk, base);
    if (base + 1 < n) v1 = packval(cnt, msk, base + 1);
    if (base + 2 < n) v2 = packval(cnt, msk, base + 2);
    if (base + 3 < n) v3 = packval(cnt, msk, base + 3);
    ull s = v0 + v1 + v2 + v3;
    sums[t] = s; __syncthreads();
    for (int o = 1; o < 256; o <<= 1) {
        ull x = (t >= o) ? sums[t - o] : 0;
        __syncthreads();
        sums[t] += x;
        __syncthreads();
    }
    ull run = blockbase + (sums[t] - s);
    #pragma unroll
    for (int j = 0; j < 4; j++) {
        int i = base + j;
        if (i < n) {
            off[i] = (int)(run & 0xffffffffu);
            msk[i] = (int)(run >> 32);
            run += (j == 0 ? v0 : j == 1 ? v1 : j == 2 ? v2 : v3);
        }
    }
}

// ---------------- fused CSR fill (atomic-free) + GAT layer-1 node -----------

__global__ __launch_bounds__(256) void k_fill_node1(
    const int* __restrict__ eidx, const int* __restrict__ rank, int E, int N,
    const int* __restrict__ off, int* __restrict__ esrc,
    const float* __restrict__ xF, const float* __restrict__ W,
    const float* __restrict__ atS, const float* __restrict__ atD,
    __hip_bfloat162* __restrict__ h2, float* __restrict__ as_, float* __restrict__ ad_,
    int gfill) {
    __shared__ float xl[64 * 4];
    int b = blockIdx.x;
    if (b < gfill) {
        int e = b * 256 + threadIdx.x;
        if (e < E) {
            int s = eidx[e], d = eidx[E + e];
            if ((unsigned)d < (unsigned)N && (unsigned)s < (unsigned)N)
                esrc[off[d] + rank[e]] = s;
        } else if (e < E + N) {
            int i = e - E;
            esrc[off[i + 1] - 1] = i;   // self-loop in the last slot
        }
        return;
    }
    int t = threadIdx.x, lane = t & 63, w = t >> 6;
    int nblk = (b - gfill) * 64;
    int cnt = N - nblk; if (cnt > 64) cnt = 64;

    if (t < 64) xl[t * 4 + 3] = 0.f;
    for (int i = t; i < cnt * 3; i += 256) xl[(i / 3) * 4 + (i % 3)] = xF[(size_t)nblk * 3 + i];

    const float2* W2 = (const float2*)W;
    float2 Wr0 = W2[0 * 64 + lane], Wr1 = W2[1 * 64 + lane], Wr2 = W2[2 * 64 + lane];
    float2 aSp = ((const float2*)atS)[lane];
    float2 aDp = ((const float2*)atD)[lane];
    int hd = lane >> 4;
    __syncthreads();

    for (int i = 0; i < 16; i++) {
        int n = nblk + w * 16 + i;
        if (n >= N) break;
        float4 xv = ((const float4*)xl)[w * 16 + i];
        float acc0 = xv.x * Wr0.x + xv.y * Wr1.x + xv.z * Wr2.x;
        float acc1 = xv.x * Wr0.y + xv.y * Wr1.y + xv.z * Wr2.y;
        __hip_bfloat162 hv; hv.x = __float2bfloat16(acc0); hv.y = __float2bfloat16(acc1);
        h2[(size_t)n * 64 + lane] = hv;
        float p = acc0 * aSp.x + acc1 * aSp.y;
        float q = acc0 * aDp.x + acc1 * aDp.y;
        #pragma unroll
        for (int o = 1; o < 16; o <<= 1) { p += __shfl_xor(p, o, 64); q += __shfl_xor(q, o, 64); }
        if ((lane & 15) == 0) { as_[n * 4 + hd] = p; ad_[n * 4 + hd] = q; }
    }
}

// ---------------- GAT node kernel (layers 2,3) ------------------------------
// Round-15: input activations now bf16x2 (halved traffic); converted to f32
// during the LDS stage.

__global__ __launch_bounds__(256) void k_node_mid(
    const __hip_bfloat162* __restrict__ xin, const float* __restrict__ W,
    const float* __restrict__ atS, const float* __restrict__ atD,
    int N, __hip_bfloat162* __restrict__ h2, float* __restrict__ as_, float* __restrict__ ad_) {
    __shared__ float xl[64 * 32];
    int t = threadIdx.x, lane = t & 63, w = t >> 6;
    int nblk = blockIdx.x * 64;
    int cnt = N - nblk; if (cnt > 64) cnt = 64;

    {
        const __hip_bfloat162* g2 = xin + (size_t)nblk * 16;
        int lim = cnt * 16;
        for (int idx = t; idx < lim; idx += 256) {
            __hip_bfloat162 hb = g2[idx];
            xl[2 * idx]     = bf2f(hb.x);
            xl[2 * idx + 1] = bf2f(hb.y);
        }
    }

    const float2* W2 = (const float2*)W;
    float2 Wr[32];
    #pragma unroll
    for (int k = 0; k < 32; k++) Wr[k] = W2[k * 64 + lane];
    float2 aSp = ((const float2*)atS)[lane];
    float2 aDp = ((const float2*)atD)[lane];
    int hd = lane >> 4;
    __syncthreads();

    for (int i = 0; i < 16; i++) {
        int n = nblk + w * 16 + i;
        if (n >= N) break;
        const float4* xv4 = (const float4*)&xl[(w * 16 + i) * 32];
        float acc0 = 0.f, acc1 = 0.f;
        #pragma unroll
        for (int kk = 0; kk < 8; kk++) {
            float4 xv = xv4[kk];
            acc0 += xv.x * Wr[4*kk+0].x; acc1 += xv.x * Wr[4*kk+0].y;
            acc0 += xv.y * Wr[4*kk+1].x; acc1 += xv.y * Wr[4*kk+1].y;
            acc0 += xv.z * Wr[4*kk+2].x; acc1 += xv.z * Wr[4*kk+2].y;
            acc0 += xv.w * Wr[4*kk+3].x; acc1 += xv.w * Wr[4*kk+3].y;
        }
        __hip_bfloat162 hv; hv.x = __float2bfloat16(acc0); hv.y = __float2bfloat16(acc1);
        h2[(size_t)n * 64 + lane] = hv;
        float p = acc0 * aSp.x + acc1 * aSp.y;
        float q = acc0 * aDp.x + acc1 * aDp.y;
        #pragma unroll
        for (int o = 1; o < 16; o <<= 1) { p += __shfl_xor(p, o, 64); q += __shfl_xor(q, o, 64); }
        if ((lane & 15) == 0) { as_[n * 4 + hd] = p; ad_[n * 4 + hd] = q; }
    }
}

// ---------------- GAT edge kernel (round-14 structure; bf16 output) ---------
// k_edge is CONVERGED at ~55 us: rounds 9/11/14 (3 structurally different
// VALU/LDS mixes) all land at 55-56 us with FETCH ~130 MB -> bound by the
// memory system's throughput for random 256 B h2-row gathers (~2.4 TB/s).

constexpr int FCAP  = 64;
constexpr int FCAPP = 68;

__global__ __launch_bounds__(256) void k_edge(
    const __hip_bfloat162* __restrict__ h2, const float* __restrict__ as_,
    const float* __restrict__ ad_, const int* __restrict__ off,
    const int* __restrict__ esrc, const float* __restrict__ bias,
    int N, __hip_bfloat162* __restrict__ xout) {
    __shared__ __align__(16) float alphaS[4][4 * FCAPP];
    __shared__ __align__(16) int   srcS[4][FCAP];
    int t = threadIdx.x, lane = t & 63, w = t >> 6;
    int n = blockIdx.x * 4 + w;
    if (n >= N) return;
    int beg = off[n], end = off[n + 1];
    int deg = end - beg;
    float4 adn = ((const float4*)ad_)[n];
    const float4* as4 = (const float4*)as_;
    int hd = lane >> 4;

    float acc0 = 0.f, acc1 = 0.f;

    if (deg <= 16) {
        int e = lane >> 2, h = lane & 3;
        int s_e = n;
        float v = -1e30f;
        if (e < deg) {
            int s = esrc[beg + e];
            if ((unsigned)s < (unsigned)N) {
                s_e = s;
                float asv = as_[s * 4 + h];
                float adv = h == 0 ? adn.x : h == 1 ? adn.y : h == 2 ? adn.z : adn.w;
                v = asv + adv; v = v >= 0.f ? v : 0.2f * v;
            }
        }
        float m = v;
        #pragma unroll
        for (int o = 4; o < 64; o <<= 1) m = fmaxf(m, __shfl_xor(m, o, 64));
        float ex = (v > -1e29f) ? __expf(v - m) : 0.f;   // pad/invalid -> 0
        float ssum = ex;
        #pragma unroll
        for (int o = 4; o < 64; o <<= 1) ssum += __shfl_xor(ssum, o, 64);
        float inv = 1.f / (ssum + 1e-16f);
        float invH = __shfl(inv, hd, 64);

        alphaS[w][h * 20 + e] = ex;
        if (h == 0) srcS[w][e] = s_e;

        #pragma unroll
        for (int c = 0; c < 4; c++) {
            if (4 * c < deg) {
                float4 wt4 = *(const float4*)&alphaS[w][hd * 20 + 4 * c];
                int4   s4  = *(const int4*)&srcS[w][4 * c];
                __hip_bfloat162 g0 = h2[(size_t)s4.x * 64 + lane];
                __hip_bfloat162 g1 = h2[(size_t)s4.y * 64 + lane];
                __hip_bfloat162 g2 = h2[(size_t)s4.z * 64 + lane];
                __hip_bfloat162 g3 = h2[(size_t)s4.w * 64 + lane];
                acc0 += wt4.x * bf2f(g0.x) + wt4.y * bf2f(g1.x)
                      + wt4.z * bf2f(g2.x) + wt4.w * bf2f(g3.x);
                acc1 += wt4.x * bf2f(g0.y) + wt4.y * bf2f(g1.y)
                      + wt4.z * bf2f(g2.y) + wt4.w * bf2f(g3.y);
            }
        }
        acc0 *= invH; acc1 *= invH;
    } else {
        bool fits = (deg <= FCAP);
        float m0 = -1e30f, m1 = -1e30f, m2 = -1e30f, m3 = -1e30f;
        for (int e = beg + lane; e < end; e += 64) {
            int s = esrc[e];
            if ((unsigned)s >= (unsigned)N) continue;
            float4 a = as4[s];
            float v0 = a.x + adn.x; v0 = v0 >= 0.f ? v0 : 0.2f * v0;
            float v1 = a.y + adn.y; v1 = v1 >= 0.f ? v1 : 0.2f * v1;
            float v2 = a.z + adn.z; v2 = v2 >= 0.f ? v2 : 0.2f * v2;
            float v3 = a.w + adn.w; v3 = v3 >= 0.f ? v3 : 0.2f * v3;
            m0 = fmaxf(m0, v0); m1 = fmaxf(m1, v1); m2 = fmaxf(m2, v2); m3 = fmaxf(m3, v3);
        }
        #pragma unroll
        for (int o = 1; o < 64; o <<= 1) {
            m0 = fmaxf(m0, __shfl_xor(m0, o, 64));
            m1 = fmaxf(m1, __shfl_xor(m1, o, 64));
            m2 = fmaxf(m2, __shfl_xor(m2, o, 64));
            m3 = fmaxf(m3, __shfl_xor(m3, o, 64));
        }
        float s0 = 0.f, s1 = 0.f, s2 = 0.f, s3 = 0.f;
        for (int e = beg + lane; e < end; e += 64) {
            int s = esrc[e];
            bool ok = (unsigned)s < (unsigned)N;
            float4 a = ok ? as4[s] : make_float4(-1e30f, -1e30f, -1e30f, -1e30f);
            float v0 = a.x + adn.x; v0 = v0 >= 0.f ? v0 : 0.2f * v0;
            float v1 = a.y + adn.y; v1 = v1 >= 0.f ? v1 : 0.2f * v1;
            float v2 = a.z + adn.z; v2 = v2 >= 0.f ? v2 : 0.2f * v2;
            float v3 = a.w + adn.w; v3 = v3 >= 0.f ? v3 : 0.2f * v3;
            float e0 = __expf(v0 - m0), e1 = __expf(v1 - m1);
            float e2 = __expf(v2 - m2), e3 = __expf(v3 - m3);
            s0 += e0; s1 += e1; s2 += e2; s3 += e3;
            if (fits) {
                int i = e - beg;
                srcS[w][i] = ok ? s : n;
                alphaS[w][0 * FCAPP + i] = e0;
                alphaS[w][1 * FCAPP + i] = e1;
                alphaS[w][2 * FCAPP + i] = e2;
                alphaS[w][3 * FCAPP + i] = e3;
            }
        }
        #pragma unroll
        for (int o = 1; o < 64; o <<= 1) {
            s0 += __shfl_xor(s0, o, 64); s1 += __shfl_xor(s1, o, 64);
            s2 += __shfl_xor(s2, o, 64); s3 += __shfl_xor(s3, o, 64);
        }
        float i0 = 1.f / (s0 + 1e-16f), i1 = 1.f / (s1 + 1e-16f);
        float i2 = 1.f / (s2 + 1e-16f), i3 = 1.f / (s3 + 1e-16f);
        float invH = hd == 0 ? i0 : hd == 1 ? i1 : hd == 2 ? i2 : i3;
        if (fits) {
            for (int i = 0; i < deg; i++) {
                int s = srcS[w][i];
                float wt = alphaS[w][hd * FCAPP + i];
                __hip_bfloat162 hv = h2[(size_t)s * 64 + lane];
                acc0 += wt * bf2f(hv.x);
                acc1 += wt * bf2f(hv.y);
            }
        } else {
            float mH  = hd == 0 ? m0 : hd == 1 ? m1 : hd == 2 ? m2 : m3;
            float adH = hd == 0 ? adn.x : hd == 1 ? adn.y : hd == 2 ? adn.z : adn.w;
            for (int e = beg; e < end; e++) {
                int s = esrc[e];
                if ((unsigned)s >= (unsigned)N) continue;
                float4 a = as4[s];
                float aH = hd == 0 ? a.x : hd == 1 ? a.y : hd == 2 ? a.z : a.w;
                float v = aH + adH; v = v >= 0.f ? v : 0.2f * v;
                float wt = __expf(v - mH);
                __hip_bfloat162 hv = h2[(size_t)s * 64 + lane];
                acc0 += wt * bf2f(hv.x);
                acc1 += wt * bf2f(hv.y);
            }
        }
        acc0 *= invH; acc1 *= invH;
    }
    acc0 += __shfl_xor(acc0, 16, 64); acc0 += __shfl_xor(acc0, 32, 64);
    acc1 += __shfl_xor(acc1, 16, 64); acc1 += __shfl_xor(acc1, 32, 64);
    if (lane < 16) {
        float o0 = acc0 * 0.25f + bias[2 * lane];     o0 = o0 >= 0.f ? o0 : 0.01f * o0;
        float o1 = acc1 * 0.25f + bias[2 * lane + 1]; o1 = o1 >= 0.f ? o1 : 0.01f * o1;
        __hip_bfloat162 ov; ov.x = __float2bfloat16(o0); ov.y = __float2bfloat16(o1);
        xout[(size_t)n * 16 + lane] = ov;
    }
}

// ---------------- MLP + output scatter --------------------------------------
// Round-15: single IN-PLACE act buffer (each thread owns column t; all layer
// reads land in registers before the writes) -> LDS 53->37 KB -> 4 blocks/CU.
// x3 input now bf16x2.

__global__ __launch_bounds__(128) void k_mlp(
    const float* __restrict__ xF, const __hip_bfloat162* __restrict__ x3,
    const float* __restrict__ mW1, const float* __restrict__ mb1,
    const float* __restrict__ mW2, const float* __restrict__ mb2,
    const float* __restrict__ mW3, const float* __restrict__ mb3,
    const float* __restrict__ mW4, const float* __restrict__ mb4,
    const float* __restrict__ mW5, const float* __restrict__ mb5,
    const int* __restrict__ smask, const int* __restrict__ totals,
    const int* __restrict__ flag, int N, void* __restrict__ out) {
    __shared__ float W1[35 * 32], W2[1024], W3[1024], W4[1024], W5[32 * 12];
    __shared__ float B1[32], B2[32], B3[32], B4[32], B5[12];
    __shared__ float act[35 * 128];
    int t = threadIdx.x;
    for (int i = t; i < 1120; i += 128) W1[i] = mW1[i];
    for (int i = t; i < 1024; i += 128) { W2[i] = mW2[i]; W3[i] = mW3[i]; W4[i] = mW4[i]; }
    for (int i = t; i < 384; i += 128) W5[i] = mW5[i];
    if (t < 32) { B1[t] = mb1[t]; B2[t] = mb2[t]; B3[t] = mb3[t]; B4[t] = mb4[t]; }
    if (t < 12) B5[t] = mb5[t];
    __syncthreads();

    int n = blockIdx.x * 128 + t;
    bool alive = (n < N);
    float x0 = 0.f;
    if (alive) {
        x0 = xF[n * 3 + 0];
        act[0 * 128 + t] = x0;
        act[1 * 128 + t] = xF[n * 3 + 1];
        act[2 * 128 + t] = xF[n * 3 + 2];
        for (int i = 0; i < 16; i++) {
            __hip_bfloat162 hb = x3[(size_t)n * 16 + i];
            act[(3 + 2 * i) * 128 + t] = bf2f(hb.x);
            act[(4 + 2 * i) * 128 + t] = bf2f(hb.y);
        }
    }

    float acc[32];

    // L1: 35 -> 32 (in-place: reads complete into acc before writes)
    #pragma unroll
    for (int o = 0; o < 32; o++) acc[o] = B1[o];
    #pragma unroll 2
    for (int i = 0; i < 35; i++) {
        float ai = act[i * 128 + t];
        const float4* w4 = (const float4*)&W1[i * 32];
        #pragma unroll
        for (int q = 0; q < 8; q++) {
            float4 w = w4[q];
            acc[q*4+0] += ai * w.x; acc[q*4+1] += ai * w.y;
            acc[q*4+2] += ai * w.z; acc[q*4+3] += ai * w.w;
        }
    }
    #pragma unroll
    for (int o = 0; o < 32; o++) { float v = acc[o]; act[o * 128 + t] = (v >= 0.f ? v : 0.01f * v); }

    // L2
    #pragma unroll
    for (int o = 0; o < 32; o++) acc[o] = B2[o];
    #pragma unroll 2
    for (int i = 0; i < 32; i++) {
        float ai = act[i * 128 + t];
        const float4* w4 = (const float4*)&W2[i * 32];
        #pragma unroll
        for (int q = 0; q < 8; q++) {
            float4 w = w4[q];
            acc[q*4+0] += ai * w.x; acc[q*4+1] += ai * w.y;
            acc[q*4+2] += ai * w.z; acc[q*4+3] += ai * w.w;
        }
    }
    #pragma unroll
    for (int o = 0; o < 32; o++) { float v = acc[o]; act[o * 128 + t] = (v >= 0.f ? v : 0.01f * v); }

    // L3
    #pragma unroll
    for (int o = 0; o < 32; o++) acc[o] = B3[o];
    #pragma unroll 2
    for (int i = 0; i < 32; i++) {
        float ai = act[i * 128 + t];
        const float4* w4 = (const float4*)&W3[i * 32];
        #pragma unroll
        for (int q = 0; q < 8; q++) {
            float4 w = w4[q];
            acc[q*4+0] += ai * w.x; acc[q*4+1] += ai * w.y;
            acc[q*4+2] += ai * w.z; acc[q*4+3] += ai * w.w;
        }
    }
    #pragma unroll
    for (int o = 0; o < 32; o++) { float v = acc[o]; act[o * 128 + t] = (v >= 0.f ? v : 0.01f * v); }

    // L4
    #pragma unroll
    for (int o = 0; o < 32; o++) acc[o] = B4[o];
    #pragma unroll 2
    for (int i = 0; i < 32; i++) {
        float ai = act[i * 128 + t];
        const float4* w4 = (const float4*)&W4[i * 32];
        #pragma unroll
        for (int q = 0; q < 8; q++) {
            float4 w = w4[q];
            acc[q*4+0] += ai * w.x; acc[q*4+1] += ai * w.y;
            acc[q*4+2] += ai * w.z; acc[q*4+3] += ai * w.w;
        }
    }
    #pragma unroll
    for (int o = 0; o < 32; o++) { float v = acc[o]; act[o * 128 + t] = (v >= 0.f ? v : 0.01f * v); }

    // L5: 32 -> 12
    float d[12];
    #pragma unroll
    for (int o = 0; o < 12; o++) d[o] = B5[o];
    #pragma unroll 2
    for (int i = 0; i < 32; i++) {
        float ai = act[i * 128 + t];
        const float4* w4 = (const float4*)&W5[i * 12];
        #pragma unroll
        for (int q = 0; q < 3; q++) {
            float4 w = w4[q];
            d[q*4+0] += ai * w.x; d[q*4+1] += ai * w.y;
            d[q*4+2] += ai * w.z; d[q*4+3] += ai * w.w;
        }
    }
    if (!alive) return;
    #pragma unroll
    for (int o = 0; o < 12; o++) if (!(d[o] == d[o])) d[o] = 0.f;  // NaN scrub

    bool tower = (x0 == 0.0f);
    int r = smask[n];
    int Nt = *totals;
    int f32o = *flag;
    int base9, base3, rr;
    if (tower) { rr = r;     base9 = 0;      base3 = 9 * N; }
    else       { rr = n - r; base9 = 9 * Nt; base3 = 9 * N + 3 * Nt; }
    if (f32o) {
        float* o = (float*)out;
        #pragma unroll
        for (int j = 0; j < 9; j++) o[base9 + rr * 9 + j] = d[j];
        #pragma unroll
        for (int j = 0; j < 3; j++) o[base3 + rr * 3 + j] = d[9 + j];
    } else {
        __hip_bfloat16* o = (__hip_bfloat16*)out;
        #pragma unroll
        for (int j = 0; j < 9; j++) o[base9 + rr * 9 + j] = __float2bfloat16(d[j]);
        #pragma unroll
        for (int j = 0; j < 3; j++) o[base3 + rr * 3 + j] = __float2bfloat16(d[9 + j]);
    }
}

// ---------------- launch ----------------

extern "C" void kernel_launch(void* const* d_in, const int* in_sizes, int n_in,
                              void* d_out, int out_size, void* d_ws, size_t ws_size,
                              hipStream_t stream) {
    const void* xraw = d_in[0];
    const int*  eidx = (const int*)d_in[1];
    // d_in[2] edge_attr: unused

    int N  = in_sizes[0] / 3;
    int E  = in_sizes[1] / 2;
    int EE = E + N;

    Segs segs;
    int coff[22];
    int canonN = 3 * N;
    for (int i = 3; i <= 24; i++) {
        int a = i - 3;
        segs.s[a].src = d_in[i];
        segs.s[a].off = canonN;
        segs.s[a].len = in_sizes[i];
        coff[a] = canonN;
        canonN += in_sizes[i];
    }

    auto alignv = [](size_t v, size_t a) { return (v + a - 1) & ~(a - 1); };
    char* base = (char*)d_ws;
    size_t o = 0;
    float* canon = (float*)(base + o); o = alignv(o + (size_t)canonN * 4, 16);
    int* flag     = (int*)(base + o); o = alignv(o + 16, 16);
    ull* partials = (ull*)(base + o); o = alignv(o + 1024 * 8, 16);
    int* totals   = (int*)(base + o); o = alignv(o + 16, 16);
    int* off      = (int*)(base + o); o = alignv(o + (size_t)(N + 1) * 4, 16);
    int* cnt      = (int*)(base + o); o = alignv(o + (size_t)N * 4, 16);
    int* esrc     = (int*)(base + o); o = alignv(o + (size_t)EE * 4, 16);
    int* rank     = (int*)(base + o); o = alignv(o + (size_t)E * 4, 16);
    int* msk      = (int*)(base + o); o = alignv(o + (size_t)N * 4, 256);
    __hip_bfloat162* h2 = (__hip_bfloat162*)(base + o); o = alignv(o + (size_t)N * 64 * 4, 16);
    __hip_bfloat162* xb = (__hip_bfloat162*)(base + o); o = alignv(o + (size_t)N * 16 * 4, 16);
    float* as_ = (float*)(base + o); o = alignv(o + (size_t)N * 16, 16);
    float* ad_ = (float*)(base + o);

    int nb = (N + 1023) / 1024;
    int g4 = (N + 3) / 4;
    int g64 = (N + 63) / 64;
    int gM = (N + 127) / 128;
    int gfill = (EE + 255) / 256;

    int nprobe = in_sizes[0] < 4096 ? in_sizes[0] : 4096;
    hipMemsetAsync(cnt, 0, (size_t)N * 4, stream);
    k_fused<<<86 + (E + 255) / 256, 256, 0, stream>>>(xraw, 3 * N, nprobe, segs, canon,
                                                      flag, eidx, E, N, cnt, msk, rank);
    k_scan_partial64<<<nb, 256, 0, stream>>>(cnt, msk, N, partials);
    k_scan_final64<<<nb, 256, 0, stream>>>(cnt, msk, N, partials, nb, off, off + N, totals);

    float* xF = canon;
    const float* W1  = canon + coff[0];  const float* aS1 = canon + coff[1];
    const float* aD1 = canon + coff[2];  const float* b1  = canon + coff[3];
    const float* W2  = canon + coff[4];  const float* aS2 = canon + coff[5];
    const float* aD2 = canon + coff[6];  const float* b2  = canon + coff[7];
    const float* W3  = canon + coff[8];  const float* aS3 = canon + coff[9];
    const float* aD3 = canon + coff[10]; const float* b3  = canon + coff[11];

    k_fill_node1<<<gfill + g64, 256, 0, stream>>>(eidx, rank, E, N, off, esrc,
                                                  xF, W1, aS1, aD1, h2, as_, ad_, gfill);
    k_edge<<<g4, 256, 0, stream>>>(h2, as_, ad_, off, esrc, b1, N, xb);
    k_node_mid<<<g64, 256, 0, stream>>>(xb, W2, aS2, aD2, N, h2, as_, ad_);
    k_edge<<<g4, 256, 0, stream>>>(h2, as_, ad_, off, esrc, b2, N, xb);
    k_node_mid<<<g64, 256, 0, stream>>>(xb, W3, aS3, aD3, N, h2, as_, ad_);
    k_edge<<<g4, 256, 0, stream>>>(h2, as_, ad_, off, esrc, b3, N, xb);

    k_mlp<<<gM, 128, 0, stream>>>(xF, xb,
        canon + coff[12], canon + coff[13], canon + coff[14], canon + coff[15],
        canon + coff[16], canon + coff[17], canon + coff[18], canon + coff[19],
        canon + coff[20], canon + coff[21], msk, totals, flag, N, d_out);
}